// Round 6
// baseline (875.577 us; speedup 1.0000x reference)
//
#include <hip/hip_runtime.h>
#include <stdint.h>
#include <stddef.h>

// BasicNCAModel: 4 NCA steps on x[8,256,256,48], fp32 I/O.
// Per step: p = [x, dwconv(x,f0), dwconv(x,f1)] (reflect), h = leaky(p@w1^T+b1),
// d = h@w2^T, d *= fire(threefry) ; d[:, :3]=0 ; x += d.
// R6 (4th resubmit; R2-R5 benches were GPU-broker timeouts, kernel never ran):
//     R5 (convs folded into GEMM1 weights, im2col K=432 pad 448, A-frags direct
//     from bf16 x-tile in LDS) + inter-step x stored in BF16:
//       step1: xin(fp32) -> xb(ws bf16)
//       step2: xb -> d_out-as-bf16 scratch
//       step3: d_out-bf16 -> xb
//       step4: xb -> d_out (fp32, full overwrite)
//     ws usage = 254KB weights + 50.3MB bf16 buffer (vs 100.9MB in R5 — R5's
//     post-timing divergence was workspace overflow corrupting an adjacent
//     buffer across graph replays). Also halves inter-step HBM traffic.

#define B_   8
#define H_   256
#define W_   256
#define C_   48
#define F_   144
#define HID_ 256
#define PW_  64
#define NTOT (B_*H_*W_*C_)
#define XSTR 56   // padded channel stride of LDS x tile

typedef __attribute__((ext_vector_type(8))) short short8;   // 8 bf16
typedef __attribute__((ext_vector_type(4))) float f32x4;

struct U2 { unsigned x, y; };

__host__ __device__ __forceinline__ unsigned rotl32(unsigned v, int r) {
  return (v << r) | (v >> (32 - r));
}

// JAX Threefry-2x32, 20 rounds.
__host__ __device__ __forceinline__ U2 threefry2x32(unsigned k0, unsigned k1,
                                                    unsigned x0, unsigned x1) {
  const unsigned k2 = k0 ^ k1 ^ 0x1BD11BDAu;
  x0 += k0; x1 += k1;
#define TF_R(r) { x0 += x1; x1 = rotl32(x1, r); x1 ^= x0; }
  TF_R(13) TF_R(15) TF_R(26) TF_R(6)
  x0 += k1; x1 += k2 + 1u;
  TF_R(17) TF_R(29) TF_R(16) TF_R(24)
  x0 += k2; x1 += k0 + 2u;
  TF_R(13) TF_R(15) TF_R(26) TF_R(6)
  x0 += k0; x1 += k1 + 3u;
  TF_R(17) TF_R(29) TF_R(16) TF_R(24)
  x0 += k1; x1 += k2 + 4u;
  TF_R(13) TF_R(15) TF_R(26) TF_R(6)
  x0 += k2; x1 += k0 + 5u;
#undef TF_R
  U2 r; r.x = x0; r.y = x1; return r;
}

__device__ __forceinline__ unsigned short f2bf(float f) {  // RNE
  unsigned u = __float_as_uint(f);
  unsigned r = u + 0x7FFFu + ((u >> 16) & 1u);
  return (unsigned short)(r >> 16);
}
__device__ __forceinline__ unsigned packbf2(float lo, float hi) {
  return (unsigned)f2bf(lo) | ((unsigned)f2bf(hi) << 16);
}
__device__ __forceinline__ float bf2f(unsigned short u) {
  return __uint_as_float(((unsigned)u) << 16);
}

// ---- pack: B-fragment weights (bf16) ----
// w1B[((nt*14+ks)*64+lane)*8+j] = w~[o=nt*16+(lane&15)][k=ks*32+(lane>>4)*8+j]
//   with k = tap*48 + c (tap=dy*3+dx), w~ = conv-folded GEMM1 weight,
//   zero-padded for k>=432.
// w2B[((nt*8+ks)*64+lane)*8+j]  = w2[c=nt*16+(lane&15)][o=ks*32+(lane>>4)*8+j]
#define W1B_N 114688   // 256 out x 448 K
#define W2B_N 12288
__global__ void nca_pack(const float* __restrict__ w1,
                         const float* __restrict__ w2,
                         const float* __restrict__ f0,
                         const float* __restrict__ f1,
                         unsigned short* __restrict__ w1B,
                         unsigned short* __restrict__ w2B) {
  int i = blockIdx.x * 256 + threadIdx.x;
  if (i < W1B_N) {
    int ntg = i / 7168, r = i - ntg * 7168;     // 7168 = 14*64*8
    int ks = r >> 9, r2 = r & 511;
    int lane = r2 >> 3, j = r2 & 7;
    int o = ntg * 16 + (lane & 15);
    int k = ks * 32 + (lane >> 4) * 8 + j;
    float v = 0.0f;
    if (k < 432) {
      int tap = k / 48, c = k - tap * 48;
      v = w1[o * F_ + 48 + c] * f0[c * 9 + tap]
        + w1[o * F_ + 96 + c] * f1[c * 9 + tap];
      if (tap == 4) v += w1[o * F_ + c];        // identity (center) term
    }
    w1B[i] = f2bf(v);
  }
  if (i < W2B_N) {
    int nt = i >> 12, r = i & 4095;
    int ks = r >> 9, r2 = r & 511;
    int lane = r2 >> 3, j = r2 & 7;
    int c = nt * 16 + (lane & 15);
    int o = ks * 32 + (lane >> 4) * 8 + j;
    w2B[i] = f2bf(w2[c * HID_ + o]);
  }
}

// INBF/OUTBF select bf16 vs fp32 for the inter-step x buffers.
template<int INBF, int OUTBF>
__global__ __launch_bounds__(256, 4)
void nca_step(const void* __restrict__ xin_, void* __restrict__ xout_,
              const unsigned short* __restrict__ w1B,
              const float* __restrict__ b1,
              const unsigned short* __restrict__ w2B,
              unsigned ka, unsigned kb) {
  // Aliased LDS region (32768 B):
  //   xT [0,22176)  : x tile [3 rows][66 px][56 ch] bf16 (ch 48..55 pad, never read)
  //   hA [0,32768)  : GEMM2 A-frags [4mt*8ks][64 lane][8 j] bf16 (after xT dead)
  __shared__ __align__(16) char smem[32768];
  __shared__ float fireL[PW_];
  short* xT = (short*)smem;
  short* hA = (short*)smem;

  const int t = threadIdx.x;
  const int bid = blockIdx.x;
  const int wseg = bid & 3;
  const int h = (bid >> 2) & 255;
  const int b = bid >> 10;
  const int w0 = wseg * PW_;
  const int gbase = ((b * H_ + h) * W_ + w0) * C_;

  // ---- Stage: fire RNG + x tile (bf16, reflect resolved) ----
  if (t < PW_) {
    unsigned j = (unsigned)((b * H_ + h) * W_ + w0 + t);
    U2 r = threefry2x32(ka, kb, 0u, j);
    unsigned bits = r.x ^ r.y;
    fireL[t] = ((bits >> 9) > 4194304u) ? 1.0f : 0.0f;
  }
  {
    const int hr[3] = { (h == 0) ? 1 : h - 1, h, (h == 255) ? 254 : h + 1 };
#pragma unroll
    for (int g = 0; g < 10; ++g) {
      int i = t + g * 256;                  // 2376 = 3 rows * 66 px * 12 c4
      if (i < 2376) {
        int row = i / 792, rem = i - row * 792;
        int px = rem / 12, c4 = rem - px * 12;
        int w = w0 - 1 + px;
        int wg = (w < 0) ? 1 : (w > 255) ? 254 : w;
        const int gidx = ((b * H_ + hr[row]) * W_ + wg) * C_ + c4 * 4;
        uint2 d;
        if constexpr (INBF) {
          d = *(const uint2*)((const unsigned short*)xin_ + gidx);
        } else {
          const float4 v = *(const float4*)((const float*)xin_ + gidx);
          d.x = packbf2(v.x, v.y); d.y = packbf2(v.z, v.w);
        }
        *(uint2*)&xT[(row * 66 + px) * XSTR + c4 * 4] = d;
      }
    }
  }
  __syncthreads();

  // ---- GEMM1: h = leaky(im2col(x) @ w~^T + b1), 16x16x32, K=448 ----
  // A-frag for (mt,ks): lane holds A[px=mt*16+(lane&15)][k=ks*32+(lane>>4)*8 + 0..7],
  // read directly from xT: k -> (tap,c) -> xT[(dy*66 + px + dx)*XSTR + c].
  const int wv = t >> 6, lane = t & 63;
  const int c16 = lane & 15, quad = lane >> 4;
  f32x4 acc[4][4];
#pragma unroll
  for (int mt = 0; mt < 4; ++mt)
#pragma unroll
    for (int nt = 0; nt < 4; ++nt) acc[mt][nt] = f32x4{0.f, 0.f, 0.f, 0.f};

#pragma unroll
  for (int ks = 0; ks < 14; ++ks) {
    int chunk = ks * 4 + quad;              // 8-wide k-chunk index, 0..55
    if (chunk > 53) chunk = 53;             // k>=432: B is zero; clamp A to valid data
    const int tap = chunk / 6;              // 48%8==0 -> chunk never crosses a tap
    const int cst = (chunk - tap * 6) * 8;
    const int dy = tap / 3;
    const int dx = tap - dy * 3;
    const int off0 = (dy * 66 + c16 + dx) * XSTR + cst;   // shorts; mt adds 16*XSTR
    short8 a[4];
#pragma unroll
    for (int mt = 0; mt < 4; ++mt)
      a[mt] = *(const short8*)&xT[off0 + mt * (16 * XSTR)];
#pragma unroll
    for (int nt = 0; nt < 4; ++nt) {
      const int ntg = wv * 4 + nt;
      const short8 bf = *(const short8*)&w1B[(((ntg * 14 + ks) << 6) | lane) << 3];
#pragma unroll
      for (int mt = 0; mt < 4; ++mt)
        acc[mt][nt] = __builtin_amdgcn_mfma_f32_16x16x32_bf16(a[mt], bf, acc[mt][nt], 0, 0, 0);
    }
  }
  __syncthreads();   // all xT reads complete before hA (aliased) is written

  // epilogue: bias + leaky -> hA (GEMM2 A-frag layout)
#pragma unroll
  for (int nt = 0; nt < 4; ++nt) {
    const int o = (wv * 4 + nt) * 16 + c16;
    const float bias = b1[o];
    const int ks2 = o >> 5, q2 = (o & 31) >> 3, j2 = o & 7;
#pragma unroll
    for (int mt = 0; mt < 4; ++mt) {
#pragma unroll
      for (int reg = 0; reg < 4; ++reg) {
        float z = acc[mt][nt][reg] + bias;
        z = (z >= 0.f) ? z : 0.01f * z;
        const int lane2 = (quad * 4 + reg) + (q2 << 4);
        hA[((((mt * 8 + ks2) << 6) | lane2) << 3) + j2] = (short)f2bf(z);
      }
    }
  }
  __syncthreads();

  // ---- GEMM2: d = h @ w2^T ; fire & channel mask ; residual store ----
  {
    f32x4 acc2[3];
#pragma unroll
    for (int nt = 0; nt < 3; ++nt) acc2[nt] = f32x4{0.f, 0.f, 0.f, 0.f};
#pragma unroll
    for (int ks = 0; ks < 8; ++ks) {
      const short8 a2 = *(const short8*)&hA[(((wv * 8 + ks) << 6) | lane) << 3];
#pragma unroll
      for (int nt = 0; nt < 3; ++nt) {
        const short8 bf = *(const short8*)&w2B[(((nt * 8 + ks) << 6) | lane) << 3];
        acc2[nt] = __builtin_amdgcn_mfma_f32_16x16x32_bf16(a2, bf, acc2[nt], 0, 0, 0);
      }
    }
#pragma unroll
    for (int nt = 0; nt < 3; ++nt) {
      const int c = nt * 16 + c16;
#pragma unroll
      for (int reg = 0; reg < 4; ++reg) {
        const int pxl = wv * 16 + quad * 4 + reg;
        float d = acc2[nt][reg] * fireL[pxl];
        if (c < 3) d = 0.f;
        const int idx = gbase + pxl * C_ + c;
        float base;
        if constexpr (INBF) base = bf2f(((const unsigned short*)xin_)[idx]);
        else                base = ((const float*)xin_)[idx];
        const float r = base + d;
        if constexpr (OUTBF) ((unsigned short*)xout_)[idx] = f2bf(r);
        else                 ((float*)xout_)[idx] = r;
      }
    }
  }
}

extern "C" void kernel_launch(void* const* d_in, const int* in_sizes, int n_in,
                              void* d_out, int out_size, void* d_ws, size_t ws_size,
                              hipStream_t stream) {
  const float* xin = (const float*)d_in[0];
  const float* f0  = (const float*)d_in[1];
  const float* f1  = (const float*)d_in[2];
  const float* w1  = (const float*)d_in[3];
  const float* b1  = (const float*)d_in[4];
  const float* w2  = (const float*)d_in[5];
  float* xout = (float*)d_out;
  (void)in_sizes; (void)n_in; (void)out_size; (void)ws_size;

  // Per-step fire keys: folded = tf(key(42),(0,i)); k1 = tf(folded,(0,0)); xor-bits.
  unsigned ka[4], kb[4];
  for (int i = 0; i < 4; ++i) {
    U2 fold = threefry2x32(0u, 42u, 0u, (unsigned)i);
    U2 k1 = threefry2x32(fold.x, fold.y, 0u, 0u);
    ka[i] = k1.x; kb[i] = k1.y;
  }

  // ws: [w1B 229376B][w2B 24576B][xb bf16 NTOT = 50331648B]  (~50.6 MB total)
  unsigned short* w1B = (unsigned short*)d_ws;
  unsigned short* w2B = w1B + W1B_N;
  unsigned short* xb  = (unsigned short*)((char*)d_ws + (size_t)(W1B_N + W2B_N) * 2);
  // d_out's first NTOT*2 bytes double as a bf16 scratch buffer until step 4
  // overwrites all of d_out with the final fp32 result.
  unsigned short* ob  = (unsigned short*)d_out;

  const dim3 gs(B_ * H_ * (W_ / PW_));   // 8192
  const dim3 bs(256);

  nca_pack<<<(W1B_N + 255) / 256, 256, 0, stream>>>(w1, w2, f0, f1, w1B, w2B);
  nca_step<0, 1><<<gs, bs, 0, stream>>>(xin, xb,   w1B, b1, w2B, ka[0], kb[0]);
  nca_step<1, 1><<<gs, bs, 0, stream>>>(xb,  ob,   w1B, b1, w2B, ka[1], kb[1]);
  nca_step<1, 1><<<gs, bs, 0, stream>>>(ob,  xb,   w1B, b1, w2B, ka[2], kb[2]);
  nca_step<1, 0><<<gs, bs, 0, stream>>>(xb,  xout, w1B, b1, w2B, ka[3], kb[3]);
}

// Round 10
// 771.504 us; speedup vs baseline: 1.1349x; 1.1349x over previous
//
#include <hip/hip_runtime.h>
#include <stdint.h>
#include <stddef.h>

// BasicNCAModel: 4 NCA steps on x[8,256,256,48], fp32 I/O.
// Per step: p = [x, dwconv(x,f0), dwconv(x,f1)] (reflect), h = leaky(p@w1^T+b1),
// d = h@w2^T, d *= fire(threefry) ; d[:, :3]=0 ; x += d.
// R7 (3rd resubmit; rounds 7-9 benches were GPU-broker timeouts, never ran):
//     R6 + software-pipelined GEMMs. R6 measured latency-bound (MfmaUtil 22%,
//     VALU 27%, HBM 9%, all pipes idle): launch_bounds(256,4) pinned regs to
//     128 (64 VGPR + 64 acc), zero headroom -> no load hoisting; each k-step
//     serialized ~250cyc L2 latency before its 16 MFMA. Now launch_bounds(256,3)
//     (reg cap 170) + explicit one-deep double-buffer of A(ds) and B(global)
//     frags in GEMM1/GEMM2: loads of k+1 fly under MFMAs of k.

#define B_   8
#define H_   256
#define W_   256
#define C_   48
#define F_   144
#define HID_ 256
#define PW_  64
#define NTOT (B_*H_*W_*C_)
#define XSTR 56   // padded channel stride of LDS x tile

typedef __attribute__((ext_vector_type(8))) short short8;   // 8 bf16
typedef __attribute__((ext_vector_type(4))) float f32x4;

struct U2 { unsigned x, y; };

__host__ __device__ __forceinline__ unsigned rotl32(unsigned v, int r) {
  return (v << r) | (v >> (32 - r));
}

// JAX Threefry-2x32, 20 rounds.
__host__ __device__ __forceinline__ U2 threefry2x32(unsigned k0, unsigned k1,
                                                    unsigned x0, unsigned x1) {
  const unsigned k2 = k0 ^ k1 ^ 0x1BD11BDAu;
  x0 += k0; x1 += k1;
#define TF_R(r) { x0 += x1; x1 = rotl32(x1, r); x1 ^= x0; }
  TF_R(13) TF_R(15) TF_R(26) TF_R(6)
  x0 += k1; x1 += k2 + 1u;
  TF_R(17) TF_R(29) TF_R(16) TF_R(24)
  x0 += k2; x1 += k0 + 2u;
  TF_R(13) TF_R(15) TF_R(26) TF_R(6)
  x0 += k0; x1 += k1 + 3u;
  TF_R(17) TF_R(29) TF_R(16) TF_R(24)
  x0 += k1; x1 += k2 + 4u;
  TF_R(13) TF_R(15) TF_R(26) TF_R(6)
  x0 += k2; x1 += k0 + 5u;
#undef TF_R
  U2 r; r.x = x0; r.y = x1; return r;
}

__device__ __forceinline__ unsigned short f2bf(float f) {  // RNE
  unsigned u = __float_as_uint(f);
  unsigned r = u + 0x7FFFu + ((u >> 16) & 1u);
  return (unsigned short)(r >> 16);
}
__device__ __forceinline__ unsigned packbf2(float lo, float hi) {
  return (unsigned)f2bf(lo) | ((unsigned)f2bf(hi) << 16);
}
__device__ __forceinline__ float bf2f(unsigned short u) {
  return __uint_as_float(((unsigned)u) << 16);
}

// ---- pack: B-fragment weights (bf16) ----
// w1B[((nt*14+ks)*64+lane)*8+j] = w~[o=nt*16+(lane&15)][k=ks*32+(lane>>4)*8+j]
//   with k = tap*48 + c (tap=dy*3+dx), w~ = conv-folded GEMM1 weight,
//   zero-padded for k>=432.
// w2B[((nt*8+ks)*64+lane)*8+j]  = w2[c=nt*16+(lane&15)][o=ks*32+(lane>>4)*8+j]
#define W1B_N 114688   // 256 out x 448 K
#define W2B_N 12288
__global__ void nca_pack(const float* __restrict__ w1,
                         const float* __restrict__ w2,
                         const float* __restrict__ f0,
                         const float* __restrict__ f1,
                         unsigned short* __restrict__ w1B,
                         unsigned short* __restrict__ w2B) {
  int i = blockIdx.x * 256 + threadIdx.x;
  if (i < W1B_N) {
    int ntg = i / 7168, r = i - ntg * 7168;     // 7168 = 14*64*8
    int ks = r >> 9, r2 = r & 511;
    int lane = r2 >> 3, j = r2 & 7;
    int o = ntg * 16 + (lane & 15);
    int k = ks * 32 + (lane >> 4) * 8 + j;
    float v = 0.0f;
    if (k < 432) {
      int tap = k / 48, c = k - tap * 48;
      v = w1[o * F_ + 48 + c] * f0[c * 9 + tap]
        + w1[o * F_ + 96 + c] * f1[c * 9 + tap];
      if (tap == 4) v += w1[o * F_ + c];        // identity (center) term
    }
    w1B[i] = f2bf(v);
  }
  if (i < W2B_N) {
    int nt = i >> 12, r = i & 4095;
    int ks = r >> 9, r2 = r & 511;
    int lane = r2 >> 3, j = r2 & 7;
    int c = nt * 16 + (lane & 15);
    int o = ks * 32 + (lane >> 4) * 8 + j;
    w2B[i] = f2bf(w2[c * HID_ + o]);
  }
}

// A-frag LDS offset (shorts) for an 8-wide k-chunk of the im2col GEMM1.
__device__ __forceinline__ int aoff(int chunk, int c16) {
  if (chunk > 53) chunk = 53;   // k>=432: B is zero; clamp A to valid data
  const int tap = chunk / 6;    // 48%8==0 -> chunk never crosses a tap
  const int cst = (chunk - tap * 6) * 8;
  const int dy = tap / 3;
  const int dx = tap - dy * 3;
  return (dy * 66 + c16 + dx) * XSTR + cst;
}

// INBF/OUTBF select bf16 vs fp32 for the inter-step x buffers.
template<int INBF, int OUTBF>
__global__ __launch_bounds__(256, 3)
void nca_step(const void* __restrict__ xin_, void* __restrict__ xout_,
              const unsigned short* __restrict__ w1B,
              const float* __restrict__ b1,
              const unsigned short* __restrict__ w2Bp,
              unsigned ka, unsigned kb) {
  // Aliased LDS region (32768 B):
  //   xT [0,22176)  : x tile [3 rows][66 px][56 ch] bf16 (ch 48..55 pad, never read)
  //   hA [0,32768)  : GEMM2 A-frags [4mt*8ks][64 lane][8 j] bf16 (after xT dead)
  __shared__ __align__(16) char smem[32768];
  __shared__ float fireL[PW_];
  short* xT = (short*)smem;
  short* hA = (short*)smem;

  const int t = threadIdx.x;
  const int bid = blockIdx.x;
  const int wseg = bid & 3;
  const int h = (bid >> 2) & 255;
  const int b = bid >> 10;
  const int w0 = wseg * PW_;
  const int gbase = ((b * H_ + h) * W_ + w0) * C_;

  // ---- Stage: fire RNG + x tile (bf16, reflect resolved) ----
  if (t < PW_) {
    unsigned j = (unsigned)((b * H_ + h) * W_ + w0 + t);
    U2 r = threefry2x32(ka, kb, 0u, j);
    unsigned bits = r.x ^ r.y;
    fireL[t] = ((bits >> 9) > 4194304u) ? 1.0f : 0.0f;
  }
  {
    const int hr[3] = { (h == 0) ? 1 : h - 1, h, (h == 255) ? 254 : h + 1 };
#pragma unroll
    for (int g = 0; g < 10; ++g) {
      int i = t + g * 256;                  // 2376 = 3 rows * 66 px * 12 c4
      if (i < 2376) {
        int row = i / 792, rem = i - row * 792;
        int px = rem / 12, c4 = rem - px * 12;
        int w = w0 - 1 + px;
        int wg = (w < 0) ? 1 : (w > 255) ? 254 : w;
        const int gidx = ((b * H_ + hr[row]) * W_ + wg) * C_ + c4 * 4;
        uint2 d;
        if constexpr (INBF) {
          d = *(const uint2*)((const unsigned short*)xin_ + gidx);
        } else {
          const float4 v = *(const float4*)((const float*)xin_ + gidx);
          d.x = packbf2(v.x, v.y); d.y = packbf2(v.z, v.w);
        }
        *(uint2*)&xT[(row * 66 + px) * XSTR + c4 * 4] = d;
      }
    }
  }
  __syncthreads();

  // ---- GEMM1: h = leaky(im2col(x) @ w~^T + b1), 16x16x32, K=448 ----
  // A-frag for (mt,ks): lane holds A[px=mt*16+(lane&15)][k=ks*32+(lane>>4)*8 + 0..7],
  // read directly from xT. One-deep software pipeline: loads of ks+1 are issued
  // before the 16 MFMAs of ks, hiding LDS (~120cy) and L2 (~250cy) latency.
  const int wv = t >> 6, lane = t & 63;
  const int c16 = lane & 15, quad = lane >> 4;
  f32x4 acc[4][4];
#pragma unroll
  for (int mt = 0; mt < 4; ++mt)
#pragma unroll
    for (int nt = 0; nt < 4; ++nt) acc[mt][nt] = f32x4{0.f, 0.f, 0.f, 0.f};

#define LDA1(dst, ks) { const int o_ = aoff((ks) * 4 + quad, c16); \
  _Pragma("unroll") for (int mt = 0; mt < 4; ++mt) \
    dst[mt] = *(const short8*)&xT[o_ + mt * (16 * XSTR)]; }
#define LDB1(dst, ks) { _Pragma("unroll") for (int nt = 0; nt < 4; ++nt) \
  dst[nt] = *(const short8*)&w1B[((((wv * 4 + nt) * 14 + (ks)) << 6) | lane) << 3]; }
#define MM1(aa, bb) { _Pragma("unroll") for (int nt = 0; nt < 4; ++nt) \
  _Pragma("unroll") for (int mt = 0; mt < 4; ++mt) \
    acc[mt][nt] = __builtin_amdgcn_mfma_f32_16x16x32_bf16(aa[mt], bb[nt], acc[mt][nt], 0, 0, 0); }

  {
    short8 aA[4], aB[4], bA[4], bB[4];
    LDA1(aA, 0) LDB1(bA, 0)
#pragma unroll
    for (int kp = 0; kp < 7; ++kp) {
      LDA1(aB, 2 * kp + 1) LDB1(bB, 2 * kp + 1)
      MM1(aA, bA)
      if (kp < 6) { LDA1(aA, 2 * kp + 2) LDB1(bA, 2 * kp + 2) }
      MM1(aB, bB)
    }
  }
#undef LDA1
#undef LDB1
#undef MM1
  __syncthreads();   // all xT reads complete before hA (aliased) is written

  // epilogue: bias + leaky -> hA (GEMM2 A-frag layout)
#pragma unroll
  for (int nt = 0; nt < 4; ++nt) {
    const int o = (wv * 4 + nt) * 16 + c16;
    const float bias = b1[o];
    const int ks2 = o >> 5, q2 = (o & 31) >> 3, j2 = o & 7;
#pragma unroll
    for (int mt = 0; mt < 4; ++mt) {
#pragma unroll
      for (int reg = 0; reg < 4; ++reg) {
        float z = acc[mt][nt][reg] + bias;
        z = (z >= 0.f) ? z : 0.01f * z;
        const int lane2 = (quad * 4 + reg) + (q2 << 4);
        hA[((((mt * 8 + ks2) << 6) | lane2) << 3) + j2] = (short)f2bf(z);
      }
    }
  }
  __syncthreads();

  // ---- GEMM2: d = h @ w2^T ; fire & channel mask ; residual store ----
  {
    f32x4 acc2[3];
#pragma unroll
    for (int nt = 0; nt < 3; ++nt) acc2[nt] = f32x4{0.f, 0.f, 0.f, 0.f};

#define LDH2(dst, ks) dst = *(const short8*)&hA[(((wv * 8 + (ks)) << 6) | lane) << 3];
#define LDW2(dst, ks) { _Pragma("unroll") for (int nt = 0; nt < 3; ++nt) \
  dst[nt] = *(const short8*)&w2Bp[((((nt) * 8 + (ks)) << 6) | lane) << 3]; }
#define MM2(hh, ww) { _Pragma("unroll") for (int nt = 0; nt < 3; ++nt) \
  acc2[nt] = __builtin_amdgcn_mfma_f32_16x16x32_bf16(hh, ww[nt], acc2[nt], 0, 0, 0); }

    short8 hAx, hBx, cA[3], cB[3];
    LDH2(hAx, 0) LDW2(cA, 0)
#pragma unroll
    for (int kp = 0; kp < 4; ++kp) {
      LDH2(hBx, 2 * kp + 1) LDW2(cB, 2 * kp + 1)
      MM2(hAx, cA)
      if (kp < 3) { LDH2(hAx, 2 * kp + 2) LDW2(cA, 2 * kp + 2) }
      MM2(hBx, cB)
    }
#undef LDH2
#undef LDW2
#undef MM2

#pragma unroll
    for (int nt = 0; nt < 3; ++nt) {
      const int c = nt * 16 + c16;
#pragma unroll
      for (int reg = 0; reg < 4; ++reg) {
        const int pxl = wv * 16 + quad * 4 + reg;
        float d = acc2[nt][reg] * fireL[pxl];
        if (c < 3) d = 0.f;
        const int idx = gbase + pxl * C_ + c;
        float base;
        if constexpr (INBF) base = bf2f(((const unsigned short*)xin_)[idx]);
        else                base = ((const float*)xin_)[idx];
        const float r = base + d;
        if constexpr (OUTBF) ((unsigned short*)xout_)[idx] = f2bf(r);
        else                 ((float*)xout_)[idx] = r;
      }
    }
  }
}

extern "C" void kernel_launch(void* const* d_in, const int* in_sizes, int n_in,
                              void* d_out, int out_size, void* d_ws, size_t ws_size,
                              hipStream_t stream) {
  const float* xin = (const float*)d_in[0];
  const float* f0  = (const float*)d_in[1];
  const float* f1  = (const float*)d_in[2];
  const float* w1  = (const float*)d_in[3];
  const float* b1  = (const float*)d_in[4];
  const float* w2  = (const float*)d_in[5];
  float* xout = (float*)d_out;
  (void)in_sizes; (void)n_in; (void)out_size; (void)ws_size;

  // Per-step fire keys: folded = tf(key(42),(0,i)); k1 = tf(folded,(0,0)); xor-bits.
  unsigned ka[4], kb[4];
  for (int i = 0; i < 4; ++i) {
    U2 fold = threefry2x32(0u, 42u, 0u, (unsigned)i);
    U2 k1 = threefry2x32(fold.x, fold.y, 0u, 0u);
    ka[i] = k1.x; kb[i] = k1.y;
  }

  // ws: [w1B 229376B][w2B 24576B][xb bf16 NTOT = 50331648B]  (~50.6 MB total)
  unsigned short* w1B = (unsigned short*)d_ws;
  unsigned short* w2B = w1B + W1B_N;
  unsigned short* xb  = (unsigned short*)((char*)d_ws + (size_t)(W1B_N + W2B_N) * 2);
  // d_out's first NTOT*2 bytes double as a bf16 scratch buffer until step 4
  // overwrites all of d_out with the final fp32 result.
  unsigned short* ob  = (unsigned short*)d_out;

  const dim3 gs(B_ * H_ * (W_ / PW_));   // 8192
  const dim3 bs(256);

  nca_pack<<<(W1B_N + 255) / 256, 256, 0, stream>>>(w1, w2, f0, f1, w1B, w2B);
  nca_step<0, 1><<<gs, bs, 0, stream>>>(xin, xb,   w1B, b1, w2B, ka[0], kb[0]);
  nca_step<1, 1><<<gs, bs, 0, stream>>>(xb,  ob,   w1B, b1, w2B, ka[1], kb[1]);
  nca_step<1, 1><<<gs, bs, 0, stream>>>(ob,  xb,   w1B, b1, w2B, ka[2], kb[2]);
  nca_step<1, 0><<<gs, bs, 0, stream>>>(xb,  xout, w1B, b1, w2B, ka[3], kb[3]);
}